// Round 2
// baseline (596.623 us; speedup 1.0000x reference)
//
#include <hip/hip_runtime.h>

typedef float f32x4 __attribute__((ext_vector_type(4)));
typedef short bf16x8 __attribute__((ext_vector_type(8)));

#define T_LEN 200
#define E_DIM 64
#define H1D 80
#define H2D 40
#define T_PAD 208
#define NT1 5      // 80/16 col tiles GEMM1
#define NT2 3      // 48/16 col tiles GEMM2
// ---- ws byte offsets (all written every launch) ----
#define WS_BC    0u        // f32[5][2][64][8]  = 20480 B   (W1_B - W1_C in frag layout)
#define WS_D     20480u    // f32[5][2][64][8]  = 20480 B   (W1_D in frag layout)
#define WS_W2    40960u    // bf16[3][3][64][8] = 9216 B    (W2 padded 96x48, frag layout)
#define WS_W1EFF 50176u    // f32[64][80]       = 20480 B   (W1_A + W1_C)
#define WS_BIAS  70656u    // f32[B][80]                    (q @ W1eff + b1)

static __device__ __forceinline__ unsigned short f2bf(float x) {
  unsigned u = __builtin_bit_cast(unsigned, x);
  return (unsigned short)((u + 0x7fffu + ((u >> 16) & 1u)) >> 16);
}
static __device__ __forceinline__ float bf2f(unsigned short h) {
  unsigned u = ((unsigned)h) << 16;
  return __builtin_bit_cast(float, u);
}
static __device__ __forceinline__ float sigm(float x) {
  return __builtin_amdgcn_rcpf(1.f + __expf(-x));
}

// ---------------- setup 1: weight fragments (coalesced, run once) ----------------
__global__ __launch_bounds__(256)
void setup1(const float* __restrict__ W1, const float* __restrict__ W2,
            unsigned char* __restrict__ ws) {
  float* bc = (float*)(ws + WS_BC);
  float* dd = (float*)(ws + WS_D);
  unsigned short* w2f = (unsigned short*)(ws + WS_W2);
  float* w1e = (float*)(ws + WS_W1EFF);
  int g = blockIdx.x * 256 + threadIdx.x;
  if (g < 5120) {                       // BC + D fragments
    int nt = g >> 10;
    int rem = g & 1023;
    int ks = rem >> 9;
    int l = (rem >> 3) & 63;
    int j = g & 7;
    int e = ks * 32 + ((l >> 4) << 3) + j;
    int col = nt * 16 + (l & 15);
    bc[g] = W1[(64 + e) * H1D + col] - W1[(128 + e) * H1D + col];
    dd[g] = W1[(192 + e) * H1D + col];
  } else if (g < 9728) {                // W2 fragments (padded to 96x48)
    int h = g - 5120;
    int nt2 = h / 1536;
    int rem = h - nt2 * 1536;
    int ks2 = rem >> 9;
    int l = (rem >> 3) & 63;
    int j = h & 7;
    int k = ks2 * 32 + ((l >> 4) << 3) + j;
    int n = nt2 * 16 + (l & 15);
    float v = (k < H1D && n < H2D) ? W2[k * H2D + n] : 0.f;
    w2f[h] = f2bf(v);
  } else if (g < 14848) {               // W1eff = A + C
    int w = g - 9728;
    int e = w / 80;
    int j = w - e * 80;
    w1e[w] = W1[e * H1D + j] + W1[(128 + e) * H1D + j];
  }
}

// ---------------- setup 2: per-b bias1 = q @ W1eff + b1 ----------------
__global__ __launch_bounds__(128)
void setup2(const float* __restrict__ query, const float* __restrict__ b1,
            const unsigned char* __restrict__ ws, float* __restrict__ bias) {
  const float* w1e = (const float*)(ws + WS_W1EFF);
  const int b = blockIdx.x, j = threadIdx.x;
  if (j < H1D) {
    float s = b1[j];
    const float* q = query + (size_t)b * E_DIM;
    #pragma unroll
    for (int e = 0; e < E_DIM; ++e) s += q[e] * w1e[e * H1D + j];
    bias[(size_t)b * H1D + j] = s;
  }
}

// ---------------- main: one block (8 waves) per b ----------------
// LDS: K[208][64] bf16 swz (26624) | H1[208][80] bf16 swz (33280) | SC (832) | PP (2048) | QS (256) | B1 (320)
#define OFF_K  0
#define OFF_H1 26624
#define OFF_SC 59904
#define OFF_PP 60736
#define OFF_QS 62784
#define OFF_B1 63040
#define SMEM_TOTAL 63360

template <bool BW>
__global__ __launch_bounds__(512, 4)
void din_main(const float* __restrict__ query, const float* __restrict__ keys,
              const int* __restrict__ keys_length,
              const float* __restrict__ b1, const float* __restrict__ b2,
              const float* __restrict__ Wd, const float* __restrict__ bd,
              const unsigned char* __restrict__ ws, float* __restrict__ out) {
  __shared__ __align__(16) unsigned char smem[SMEM_TOTAL];
  unsigned char* Kb  = smem + OFF_K;
  unsigned char* H1b = smem + OFF_H1;
  float* SC = (float*)(smem + OFF_SC);
  float* PP = (float*)(smem + OFF_PP);
  float* QS = (float*)(smem + OFF_QS);
  float* B1 = (float*)(smem + OFF_B1);

  const int tid = threadIdx.x, b = blockIdx.x;
  const int lane = tid & 63, wv = tid >> 6;
  const int qq = lane >> 4, cc = lane & 15;
  const float* keyb = keys + (size_t)b * (T_LEN * E_DIM);

  if (!BW && tid < E_DIM) QS[tid] = query[(size_t)b * E_DIM + tid];

  // ---- stage keys -> bf16 LDS, XOR-swizzled rows (128B pitch) ----
  #pragma unroll
  for (int it = 0; it < 7; ++it) {
    int f = (it * 512 + tid) * 4;
    if (f < T_LEN * E_DIM) {
      const float4 v = *(const float4*)(keyb + f);
      unsigned p0 = ((unsigned)f2bf(v.y) << 16) | f2bf(v.x);
      unsigned p1 = ((unsigned)f2bf(v.w) << 16) | f2bf(v.z);
      int row = f >> 6;
      unsigned byte = ((unsigned)(f * 2)) ^ ((unsigned)(row & 7) << 4);
      *(uint2*)(Kb + byte) = make_uint2(p0, p1);
    } else if (f < T_PAD * E_DIM) {
      int row = f >> 6;
      unsigned byte = ((unsigned)(f * 2)) ^ ((unsigned)(row & 7) << 4);
      *(uint2*)(Kb + byte) = make_uint2(0u, 0u);
    }
  }

  // ---- build GEMM1 B-fragments in regs: bf16(BC + q*D), L2-hot ws ----
  const float* wsBC = (const float*)(ws + WS_BC);
  const float* wsD  = (const float*)(ws + WS_D);
  bf16x8 bfr[NT1][2];
  {
    float qv[2][8];
    #pragma unroll
    for (int ks = 0; ks < 2; ++ks) {
      const float4 qa = *(const float4*)(query + (size_t)b * E_DIM + ks * 32 + qq * 8);
      const float4 qb = *(const float4*)(query + (size_t)b * E_DIM + ks * 32 + qq * 8 + 4);
      qv[ks][0] = qa.x; qv[ks][1] = qa.y; qv[ks][2] = qa.z; qv[ks][3] = qa.w;
      qv[ks][4] = qb.x; qv[ks][5] = qb.y; qv[ks][6] = qb.z; qv[ks][7] = qb.w;
    }
    #pragma unroll
    for (int nt = 0; nt < NT1; ++nt) {
      #pragma unroll
      for (int ks = 0; ks < 2; ++ks) {
        const int base = ((nt * 2 + ks) * 64 + lane) * 8;
        const float4 c0 = *(const float4*)(wsBC + base);
        const float4 c1 = *(const float4*)(wsBC + base + 4);
        const float4 d0 = *(const float4*)(wsD + base);
        const float4 d1 = *(const float4*)(wsD + base + 4);
        bf16x8 r;
        r[0] = (short)f2bf(c0.x + qv[ks][0] * d0.x);
        r[1] = (short)f2bf(c0.y + qv[ks][1] * d0.y);
        r[2] = (short)f2bf(c0.z + qv[ks][2] * d0.z);
        r[3] = (short)f2bf(c0.w + qv[ks][3] * d0.w);
        r[4] = (short)f2bf(c1.x + qv[ks][4] * d1.x);
        r[5] = (short)f2bf(c1.y + qv[ks][5] * d1.y);
        r[6] = (short)f2bf(c1.z + qv[ks][6] * d1.z);
        r[7] = (short)f2bf(c1.w + qv[ks][7] * d1.w);
        bfr[nt][ks] = r;
      }
    }
  }

  float bia[NT1];
  if (BW) {
    const float* wbias = (const float*)(ws + WS_BIAS);
    #pragma unroll
    for (int nt = 0; nt < NT1; ++nt) bia[nt] = wbias[(size_t)b * H1D + nt * 16 + cc];
  }
  float b2c[NT2], wdl[NT2];
  #pragma unroll
  for (int nt = 0; nt < NT2; ++nt) {
    int col = nt * 16 + cc;
    b2c[nt] = (col < H2D) ? b2[col] : 0.f;
    wdl[nt] = (col < H2D) ? Wd[col] : 0.f;
  }
  const float bdv = bd[0];
  const int len = keys_length[b];

  __syncthreads();  // keys staged (and QS if !BW)

  if (!BW) {
    if (tid < H1D) {
      const float* w1e = (const float*)(ws + WS_W1EFF);
      float s = b1[tid];
      #pragma unroll
      for (int e = 0; e < E_DIM; ++e) s += QS[e] * w1e[e * H1D + tid];
      B1[tid] = s;
    }
    __syncthreads();
    #pragma unroll
    for (int nt = 0; nt < NT1; ++nt) bia[nt] = B1[nt * 16 + cc];
  }

  // ---- per-wave tiles: GEMM1 -> sigmoid -> H1(LDS, wave-private) -> GEMM2 -> score ----
  const unsigned short* wsW2 = (const unsigned short*)(ws + WS_W2);
  #pragma unroll
  for (int ti = 0; ti < 2; ++ti) {
    const int tt = wv + ti * 8;
    if (tt < 13) {
      const unsigned krow = (unsigned)(tt * 16 + cc);
      const unsigned ksw = (krow & 7u) << 4;
      bf16x8 a0 = *(const bf16x8*)(Kb + ((krow * 128 + qq * 16) ^ ksw));
      bf16x8 a1 = *(const bf16x8*)(Kb + ((krow * 128 + 64 + qq * 16) ^ ksw));
      f32x4 accs[NT1];
      #pragma unroll
      for (int nt = 0; nt < NT1; ++nt) {
        f32x4 a = {bia[nt], bia[nt], bia[nt], bia[nt]};
        a = __builtin_amdgcn_mfma_f32_16x16x32_bf16(a0, bfr[nt][0], a, 0, 0, 0);
        a = __builtin_amdgcn_mfma_f32_16x16x32_bf16(a1, bfr[nt][1], a, 0, 0, 0);
        accs[nt] = a;
      }
      // sigmoid -> H1 [row][80] bf16, XOR-swizzled (160B pitch = 5x32B blocks)
      #pragma unroll
      for (int nt = 0; nt < NT1; ++nt) {
        #pragma unroll
        for (int r = 0; r < 4; ++r) {
          int row = tt * 16 + qq * 4 + r;
          unsigned byte = ((unsigned)(row * 160 + (nt * 16 + cc) * 2)) ^ ((unsigned)(row & 7) << 4);
          *(unsigned short*)(H1b + byte) = f2bf(sigm(accs[nt][r]));
        }
      }
      // GEMM2 A-frags from own rows (same wave; compiler inserts lgkmcnt)
      const unsigned hrow = (unsigned)(tt * 16 + cc);
      const unsigned hsw = (hrow & 7u) << 4;
      const unsigned hb = hrow * 160;
      bf16x8 h0 = *(const bf16x8*)(H1b + ((hb + qq * 16) ^ hsw));
      bf16x8 h1 = *(const bf16x8*)(H1b + ((hb + 64 + qq * 16) ^ hsw));
      bf16x8 h2 = {0, 0, 0, 0, 0, 0, 0, 0};
      if (qq < 2) h2 = *(const bf16x8*)(H1b + ((hb + 128 + qq * 16) ^ hsw));
      float vr[4] = {0.f, 0.f, 0.f, 0.f};
      #pragma unroll
      for (int nt = 0; nt < NT2; ++nt) {
        bf16x8 w0 = *(const bf16x8*)(wsW2 + ((nt * 3 + 0) * 64 + lane) * 8);
        bf16x8 w1 = *(const bf16x8*)(wsW2 + ((nt * 3 + 1) * 64 + lane) * 8);
        bf16x8 w2 = *(const bf16x8*)(wsW2 + ((nt * 3 + 2) * 64 + lane) * 8);
        f32x4 a = {b2c[nt], b2c[nt], b2c[nt], b2c[nt]};
        a = __builtin_amdgcn_mfma_f32_16x16x32_bf16(h0, w0, a, 0, 0, 0);
        a = __builtin_amdgcn_mfma_f32_16x16x32_bf16(h1, w1, a, 0, 0, 0);
        a = __builtin_amdgcn_mfma_f32_16x16x32_bf16(h2, w2, a, 0, 0, 0);
        #pragma unroll
        for (int r = 0; r < 4; ++r) vr[r] += sigm(a[r]) * wdl[nt];
      }
      #pragma unroll
      for (int r = 0; r < 4; ++r) {
        float v = vr[r];
        v += __shfl_xor(v, 1);
        v += __shfl_xor(v, 2);
        v += __shfl_xor(v, 4);
        v += __shfl_xor(v, 8);
        if (cc == 0) {
          int t = tt * 16 + qq * 4 + r;
          SC[t] = (t < len) ? (bdv + v) : 0.f;
        }
      }
    }
  }
  __syncthreads();

  // ---- pooling from LDS K (bf16): out[b][e] = sum_t SC[t]*K[t][e] ----
  {
    const int e = tid & 63;
    const int t0 = tid >> 6;
    float accp = 0.f;
    #pragma unroll
    for (int i = 0; i < 25; ++i) {
      int t = t0 + i * 8;
      float s = SC[t];
      unsigned byte = ((unsigned)(t * 128 + e * 2)) ^ ((unsigned)(t & 7) << 4);
      accp += s * bf2f(*(const unsigned short*)(Kb + byte));
    }
    PP[tid] = accp;
  }
  __syncthreads();
  if (tid < E_DIM) {
    float s = 0.f;
    #pragma unroll
    for (int w = 0; w < 8; ++w) s += PP[w * 64 + tid];
    out[(size_t)b * E_DIM + tid] = s;
  }
}

extern "C" void kernel_launch(void* const* d_in, const int* in_sizes, int n_in,
                              void* d_out, int out_size, void* d_ws, size_t ws_size,
                              hipStream_t stream) {
  const float* query = (const float*)d_in[0];
  const float* keys  = (const float*)d_in[1];
  const int*   klen  = (const int*)d_in[2];
  const float* W1 = (const float*)d_in[3];
  const float* b1 = (const float*)d_in[4];
  const float* W2 = (const float*)d_in[5];
  const float* b2 = (const float*)d_in[6];
  const float* Wd = (const float*)d_in[7];
  const float* bd = (const float*)d_in[8];
  float* out = (float*)d_out;
  const int B = in_sizes[2];
  unsigned char* ws = (unsigned char*)d_ws;

  hipLaunchKernelGGL(setup1, dim3(58), dim3(256), 0, stream, W1, W2, ws);

  const size_t needBias = (size_t)WS_BIAS + (size_t)B * H1D * 4;
  if (ws_size >= needBias) {
    hipLaunchKernelGGL(setup2, dim3(B), dim3(128), 0, stream,
                       query, b1, ws, (float*)(ws + WS_BIAS));
    din_main<true><<<dim3(B), dim3(512), 0, stream>>>(query, keys, klen, b1, b2, Wd, bd, ws, out);
  } else {
    din_main<false><<<dim3(B), dim3(512), 0, stream>>>(query, keys, klen, b1, b2, Wd, bd, ws, out);
  }
}

// Round 3
// 341.050 us; speedup vs baseline: 1.7494x; 1.7494x over previous
//
#include <hip/hip_runtime.h>

typedef float f32x4 __attribute__((ext_vector_type(4)));
typedef short bf16x8 __attribute__((ext_vector_type(8)));

#define T_LEN 200
#define E_DIM 64
#define H1D 80
#define H2D 40
#define T_PAD 208
#define NT1 5      // 80/16 col tiles GEMM1
#define NT2 3      // 48/16 col tiles GEMM2
// ---- ws byte offsets (all rewritten every launch) ----
#define WS_BC    0u        // f32[5][2][64][8]  = 20480 B   (W1_B - W1_C, frag layout)
#define WS_D     20480u    // f32[5][2][64][8]  = 20480 B   (W1_D, frag layout)
#define WS_W2    40960u    // bf16[3][3][64][8] = 9216 B    (W2 padded 96x48, frag layout)
#define WS_W1EFF 50176u    // f32[64][80]       = 20480 B   (W1_A + W1_C)
#define WS_BIAS  70656u    // f32[B][80]

static __device__ __forceinline__ unsigned short f2bf(float x) {
  unsigned u = __builtin_bit_cast(unsigned, x);
  return (unsigned short)((u + 0x7fffu + ((u >> 16) & 1u)) >> 16);
}
static __device__ __forceinline__ float bf2f(unsigned short h) {
  unsigned u = ((unsigned)h) << 16;
  return __builtin_bit_cast(float, u);
}
static __device__ __forceinline__ float sigm(float x) {
  return __builtin_amdgcn_rcpf(1.f + __expf(-x));
}

// ---------------- setup 1: weight fragments (coalesced) ----------------
__global__ __launch_bounds__(256)
void setup1(const float* __restrict__ W1, const float* __restrict__ W2,
            unsigned char* __restrict__ ws) {
  float* bc = (float*)(ws + WS_BC);
  float* dd = (float*)(ws + WS_D);
  unsigned short* w2f = (unsigned short*)(ws + WS_W2);
  float* w1e = (float*)(ws + WS_W1EFF);
  int g = blockIdx.x * 256 + threadIdx.x;
  if (g < 5120) {                       // BC + D fragments
    int nt = g >> 10;
    int rem = g & 1023;
    int ks = rem >> 9;
    int l = (rem >> 3) & 63;
    int j = g & 7;
    int e = ks * 32 + ((l >> 4) << 3) + j;
    int col = nt * 16 + (l & 15);
    bc[g] = W1[(64 + e) * H1D + col] - W1[(128 + e) * H1D + col];
    dd[g] = W1[(192 + e) * H1D + col];
  } else if (g < 9728) {                // W2 fragments (padded to 96x48)
    int h = g - 5120;
    int nt2 = h / 1536;
    int rem = h - nt2 * 1536;
    int ks2 = rem >> 9;
    int l = (rem >> 3) & 63;
    int j = h & 7;
    int k = ks2 * 32 + ((l >> 4) << 3) + j;
    int n = nt2 * 16 + (l & 15);
    float v = (k < H1D && n < H2D) ? W2[k * H2D + n] : 0.f;
    w2f[h] = f2bf(v);
  } else if (g < 14848) {               // W1eff = A + C
    int w = g - 9728;
    int e = w / 80;
    int j = w - e * 80;
    w1e[w] = W1[e * H1D + j] + W1[(128 + e) * H1D + j];
  }
}

// ---------------- setup 2: per-b bias1 = q @ W1eff + b1 ----------------
__global__ __launch_bounds__(128)
void setup2(const float* __restrict__ query, const float* __restrict__ b1,
            const unsigned char* __restrict__ ws, float* __restrict__ bias) {
  const float* w1e = (const float*)(ws + WS_W1EFF);
  const int b = blockIdx.x, j = threadIdx.x;
  if (j < H1D) {
    float s = b1[j];
    const float* q = query + (size_t)b * E_DIM;
    #pragma unroll
    for (int e = 0; e < E_DIM; ++e) s += q[e] * w1e[e * H1D + j];
    bias[(size_t)b * H1D + j] = s;
  }
}

// ---------------- main: one block (8 waves) per b ----------------
#define OFF_K   0          // 26624 : K bf16 [208 rows][128B], XOR-swz
#define OFF_H1  26624      // 20480 : per-wave H1 [8 waves][16 rows][160B], XOR-swz
#define OFF_FR  47104      // 10240 : GEMM1 B-frags bf16 [5][2][64][8]
#define OFF_SC  57344      // 832
#define OFF_PP  58176      // 2048
#define OFF_QS  60224      // 256
#define OFF_B1  60480      // 320
#define SMEM_TOTAL 60800

template <bool BW>
__global__ __launch_bounds__(512, 2)
void din_main(const float* __restrict__ query, const float* __restrict__ keys,
              const int* __restrict__ keys_length,
              const float* __restrict__ b1, const float* __restrict__ b2,
              const float* __restrict__ Wd, const float* __restrict__ bd,
              const unsigned char* __restrict__ ws, float* __restrict__ out) {
  __shared__ __align__(16) unsigned char smem[SMEM_TOTAL];
  unsigned char* Kb  = smem + OFF_K;
  unsigned char* H1b = smem + OFF_H1;
  unsigned short* FR = (unsigned short*)(smem + OFF_FR);
  float* SC = (float*)(smem + OFF_SC);
  float* PP = (float*)(smem + OFF_PP);
  float* QS = (float*)(smem + OFF_QS);
  float* B1 = (float*)(smem + OFF_B1);

  const int tid = threadIdx.x, b = blockIdx.x;
  const int lane = tid & 63, wv = tid >> 6;
  const int qq = lane >> 4, cc = lane & 15;
  const float* keyb = keys + (size_t)b * (T_LEN * E_DIM);

  if (!BW && tid < E_DIM) QS[tid] = query[(size_t)b * E_DIM + tid];

  // ---- stage keys -> bf16 LDS, XOR-swizzled rows (128B pitch) ----
  #pragma unroll
  for (int it = 0; it < 7; ++it) {
    int f = (it * 512 + tid) * 4;
    if (f < T_LEN * E_DIM) {
      const float4 v = *(const float4*)(keyb + f);
      unsigned p0 = ((unsigned)f2bf(v.y) << 16) | f2bf(v.x);
      unsigned p1 = ((unsigned)f2bf(v.w) << 16) | f2bf(v.z);
      int row = f >> 6;
      unsigned byte = ((unsigned)(f * 2)) ^ ((unsigned)(row & 7) << 4);
      *(uint2*)(Kb + byte) = make_uint2(p0, p1);
    } else if (f < T_PAD * E_DIM) {
      int row = f >> 6;
      unsigned byte = ((unsigned)(f * 2)) ^ ((unsigned)(row & 7) << 4);
      *(uint2*)(Kb + byte) = make_uint2(0u, 0u);
    }
  }

  // ---- cooperative GEMM1 B-fragment build into LDS (read BC/D ONCE per block) ----
  {
    const float* wsBC = (const float*)(ws + WS_BC);
    const float* wsD  = (const float*)(ws + WS_D);
    const float* qrow = query + (size_t)b * E_DIM;
    #pragma unroll
    for (int i = 0; i < 10; ++i) {
      int f = i * 512 + tid;
      int j = f & 7, l = (f >> 3) & 63, ks = (f >> 9) & 1;
      int e = ks * 32 + ((l >> 4) << 3) + j;
      FR[f] = f2bf(wsBC[f] + qrow[e] * wsD[f]);
    }
  }

  float bia[NT1];
  if (BW) {
    const float* wbias = (const float*)(ws + WS_BIAS);
    #pragma unroll
    for (int nt = 0; nt < NT1; ++nt) bia[nt] = wbias[(size_t)b * H1D + nt * 16 + cc];
  }
  float b2c[NT2], wdl[NT2];
  #pragma unroll
  for (int nt = 0; nt < NT2; ++nt) {
    int col = nt * 16 + cc;
    b2c[nt] = (col < H2D) ? b2[col] : 0.f;
    wdl[nt] = (col < H2D) ? Wd[col] : 0.f;
  }
  const float bdv = bd[0];
  const int len = keys_length[b];

  __syncthreads();  // keys + fragments staged (and QS if !BW)

  if (!BW) {
    if (tid < H1D) {
      const float* w1e = (const float*)(ws + WS_W1EFF);
      float s = b1[tid];
      #pragma unroll
      for (int e = 0; e < E_DIM; ++e) s += QS[e] * w1e[e * H1D + tid];
      B1[tid] = s;
    }
    __syncthreads();
    #pragma unroll
    for (int nt = 0; nt < NT1; ++nt) bia[nt] = B1[nt * 16 + cc];
  }

  // ---- per-wave tiles: GEMM1 -> sigmoid -> H1(wave-private LDS) -> GEMM2 -> score ----
  const unsigned short* wsW2 = (const unsigned short*)(ws + WS_W2);
  unsigned char* H1w = H1b + wv * 2560;  // 16 rows x 160B per wave
  #pragma unroll
  for (int ti = 0; ti < 2; ++ti) {
    const int tt = wv + ti * 8;
    if (tt < 13) {
      const unsigned krow = (unsigned)(tt * 16 + cc);
      const unsigned ksw = (krow & 7u) << 4;
      bf16x8 a0 = *(const bf16x8*)(Kb + ((krow * 128 + qq * 16) ^ ksw));
      bf16x8 a1 = *(const bf16x8*)(Kb + ((krow * 128 + 64 + qq * 16) ^ ksw));
      f32x4 accs[NT1];
      #pragma unroll
      for (int nt = 0; nt < NT1; ++nt) {
        bf16x8 bf0 = *(const bf16x8*)(FR + ((nt * 2 + 0) * 64 + lane) * 8);
        bf16x8 bf1 = *(const bf16x8*)(FR + ((nt * 2 + 1) * 64 + lane) * 8);
        f32x4 a = {bia[nt], bia[nt], bia[nt], bia[nt]};
        a = __builtin_amdgcn_mfma_f32_16x16x32_bf16(a0, bf0, a, 0, 0, 0);
        a = __builtin_amdgcn_mfma_f32_16x16x32_bf16(a1, bf1, a, 0, 0, 0);
        accs[nt] = a;
      }
      // sigmoid -> H1 wave-private [rloc][80] bf16, XOR-swz on 160B pitch
      #pragma unroll
      for (int nt = 0; nt < NT1; ++nt) {
        #pragma unroll
        for (int r = 0; r < 4; ++r) {
          int rloc = qq * 4 + r;
          unsigned byte = ((unsigned)(rloc * 160 + (nt * 16 + cc) * 2)) ^ ((unsigned)(rloc & 7) << 4);
          *(unsigned short*)(H1w + byte) = f2bf(sigm(accs[nt][r]));
        }
      }
      // GEMM2 A-frags from own wave's rows
      const unsigned hsw = ((unsigned)cc & 7u) << 4;
      const unsigned hb = (unsigned)cc * 160;
      bf16x8 h0 = *(const bf16x8*)(H1w + ((hb + qq * 16) ^ hsw));
      bf16x8 h1 = *(const bf16x8*)(H1w + ((hb + 64 + qq * 16) ^ hsw));
      bf16x8 h2 = {0, 0, 0, 0, 0, 0, 0, 0};
      if (qq < 2) h2 = *(const bf16x8*)(H1w + ((hb + 128 + qq * 16) ^ hsw));
      float vr[4] = {0.f, 0.f, 0.f, 0.f};
      #pragma unroll
      for (int nt = 0; nt < NT2; ++nt) {
        bf16x8 w0 = *(const bf16x8*)(wsW2 + ((nt * 3 + 0) * 64 + lane) * 8);
        bf16x8 w1 = *(const bf16x8*)(wsW2 + ((nt * 3 + 1) * 64 + lane) * 8);
        bf16x8 w2 = *(const bf16x8*)(wsW2 + ((nt * 3 + 2) * 64 + lane) * 8);
        f32x4 a = {b2c[nt], b2c[nt], b2c[nt], b2c[nt]};
        a = __builtin_amdgcn_mfma_f32_16x16x32_bf16(h0, w0, a, 0, 0, 0);
        a = __builtin_amdgcn_mfma_f32_16x16x32_bf16(h1, w1, a, 0, 0, 0);
        a = __builtin_amdgcn_mfma_f32_16x16x32_bf16(h2, w2, a, 0, 0, 0);
        #pragma unroll
        for (int r = 0; r < 4; ++r) vr[r] += sigm(a[r]) * wdl[nt];
      }
      #pragma unroll
      for (int r = 0; r < 4; ++r) {
        float v = vr[r];
        v += __shfl_xor(v, 1);
        v += __shfl_xor(v, 2);
        v += __shfl_xor(v, 4);
        v += __shfl_xor(v, 8);
        if (cc == 0) {
          int t = tt * 16 + qq * 4 + r;
          SC[t] = (t < len) ? (bdv + v) : 0.f;
        }
      }
    }
  }
  __syncthreads();

  // ---- pooling from LDS K (bf16): out[b][e] = sum_t SC[t]*K[t][e] ----
  {
    const int e = tid & 63;
    const int t0 = tid >> 6;
    float accp = 0.f;
    #pragma unroll
    for (int i = 0; i < 25; ++i) {
      int t = t0 + i * 8;
      float s = SC[t];
      unsigned byte = ((unsigned)(t * 128 + e * 2)) ^ ((unsigned)(t & 7) << 4);
      accp += s * bf2f(*(const unsigned short*)(Kb + byte));
    }
    PP[tid] = accp;
  }
  __syncthreads();
  if (tid < E_DIM) {
    float s = 0.f;
    #pragma unroll
    for (int w = 0; w < 8; ++w) s += PP[w * 64 + tid];
    out[(size_t)b * E_DIM + tid] = s;
  }
}

extern "C" void kernel_launch(void* const* d_in, const int* in_sizes, int n_in,
                              void* d_out, int out_size, void* d_ws, size_t ws_size,
                              hipStream_t stream) {
  const float* query = (const float*)d_in[0];
  const float* keys  = (const float*)d_in[1];
  const int*   klen  = (const int*)d_in[2];
  const float* W1 = (const float*)d_in[3];
  const float* b1 = (const float*)d_in[4];
  const float* W2 = (const float*)d_in[5];
  const float* b2 = (const float*)d_in[6];
  const float* Wd = (const float*)d_in[7];
  const float* bd = (const float*)d_in[8];
  float* out = (float*)d_out;
  const int B = in_sizes[2];
  unsigned char* ws = (unsigned char*)d_ws;

  hipLaunchKernelGGL(setup1, dim3(58), dim3(256), 0, stream, W1, W2, ws);

  const size_t needBias = (size_t)WS_BIAS + (size_t)B * H1D * 4;
  if (ws_size >= needBias) {
    hipLaunchKernelGGL(setup2, dim3(B), dim3(128), 0, stream,
                       query, b1, ws, (float*)(ws + WS_BIAS));
    din_main<true><<<dim3(B), dim3(512), 0, stream>>>(query, keys, klen, b1, b2, Wd, bd, ws, out);
  } else {
    din_main<false><<<dim3(B), dim3(512), 0, stream>>>(query, keys, klen, b1, b2, Wd, bd, ws, out);
  }
}